// Round 6
// baseline (73.694 us; speedup 1.0000x reference)
//
#include <hip/hip_runtime.h>

#define B   16
#define C1  256          // channels per input
#define C2  512          // total channels after concat
#define HW  4096         // 64*64 pixels per channel
#define TCHUNK 32        // tail pixel-chunks per batch (128 pixels each)
#define CPB 8            // channels copied per copy-block
#define QSPLIT 8         // pool: eighth-channel per thread (128 vf4 = 2 KB)

typedef float vf4 __attribute__((ext_vector_type(4)));

__device__ __forceinline__ const vf4* chan_base(
    const float* __restrict__ x1, const float* __restrict__ x2, int b, int c)
{
    return (const vf4*)((c < C1) ? (x1 + (size_t)(b * C1 + c) * HW)
                                 : (x2 + (size_t)(b * C1 + (c - C1)) * HW));
}

// ---------------------------------------------------------------------------
// Kernel 1: per-(batch, channel) sum over H*W -> pooled[B*C2]
// Lane-private streams: thread g owns 128 contiguous float4 (2 KB) of channel
// g/8. Fully unrolled, 8 independent accumulators -> deep vmcnt window.
// 8 lanes per channel folded with width-8 shuffles. 256 blocks = 1/CU.
// ---------------------------------------------------------------------------
__global__ __launch_bounds__(256, 1) void pool_kernel(
    const float* __restrict__ x1, const float* __restrict__ x2,
    float* __restrict__ pooled)
{
    int g  = blockIdx.x * 256 + threadIdx.x;   // 0 .. 65535
    int cg = g >> 3;                           // 0..8191 = b*C2 + ch
    int q  = g & 7;                            // eighth within channel
    int b  = cg >> 9;
    int ch = cg & (C2 - 1);
    const vf4* p = chan_base(x1, x2, b, ch) + q * 128;

    vf4 a0 = (vf4)(0.f), a1 = (vf4)(0.f), a2 = (vf4)(0.f), a3 = (vf4)(0.f);
    vf4 a4 = (vf4)(0.f), a5 = (vf4)(0.f), a6 = (vf4)(0.f), a7 = (vf4)(0.f);
    #pragma unroll
    for (int i = 0; i < 128; i += 8) {
        a0 += p[i + 0]; a1 += p[i + 1]; a2 += p[i + 2]; a3 += p[i + 3];
        a4 += p[i + 4]; a5 += p[i + 5]; a6 += p[i + 6]; a7 += p[i + 7];
    }
    vf4 a = ((a0 + a1) + (a2 + a3)) + ((a4 + a5) + (a6 + a7));
    float s = (a.x + a.y) + (a.z + a.w);

    s += __shfl_down(s, 4, 8);
    s += __shfl_down(s, 2, 8);
    s += __shfl_down(s, 1, 8);
    if (q == 0)
        pooled[cg] = s;
}

// ---------------------------------------------------------------------------
// Kernel 2: per-batch stable descending rank-sort of pooled values.
// ---------------------------------------------------------------------------
__global__ __launch_bounds__(512) void sort_kernel(
    const float* __restrict__ pooled, int* __restrict__ idx)
{
    int b = blockIdx.x;
    int t = threadIdx.x;            // 512 threads = one per channel
    __shared__ float sp[C2];
    float v = pooled[b * C2 + t];
    sp[t] = v;
    __syncthreads();
    int rank = 0;
    for (int j = 0; j < C2; ++j) {
        float u = sp[j];
        rank += (u > v) || (u == v && j < t);
    }
    idx[b * C2 + rank] = t;
}

// ---------------------------------------------------------------------------
// Kernel 3: gather channels in sorted order; fold tail sum into channel k-1.
// Grid: [0, B*TCHUNK)    tail blocks: each owns 128 pixels exclusively,
//                        sums all 257 tail channels (8 groups x 32 f4-slots,
//                        4-way ILP), LDS-reduces, plain store. No atomics.
//       [B*TCHUNK, ...)  copy blocks: CPB channels each, unrolled so loads
//                        of the next channel overlap stores of the current.
// ---------------------------------------------------------------------------
__global__ __launch_bounds__(256) void gather_kernel(
    const float* __restrict__ x1, const float* __restrict__ x2,
    const int* __restrict__ idx, float* __restrict__ out, int k)
{
    int t   = threadIdx.x;
    int bid = blockIdx.x;
    int ntail = B * TCHUNK;

    if (bid < ntail) {
        // ---- tail block
        int b     = bid / TCHUNK;
        int chunk = bid % TCHUNK;
        int g     = t >> 5;          // channel group 0..7
        int slot  = t & 31;          // f4 slot within 128-pixel chunk
        int off   = chunk * 32 + slot;  // f4 index in channel
        int ntc   = C2 - (k - 1);    // 257 tail channels

        __shared__ int ch[C2];
        __shared__ vf4 red[8][32];
        for (int i = t; i < ntc; i += 256)
            ch[i] = idx[b * C2 + (k - 1) + i];
        __syncthreads();

        vf4 a0 = (vf4)(0.f), a1 = (vf4)(0.f), a2 = (vf4)(0.f), a3 = (vf4)(0.f);
        int j = g;
        for (; j + 24 < ntc; j += 32) {
            int c0 = ch[j], c1 = ch[j + 8], c2 = ch[j + 16], c3 = ch[j + 24];
            a0 += chan_base(x1, x2, b, c0)[off];
            a1 += chan_base(x1, x2, b, c1)[off];
            a2 += chan_base(x1, x2, b, c2)[off];
            a3 += chan_base(x1, x2, b, c3)[off];
        }
        for (; j < ntc; j += 8)
            a0 += chan_base(x1, x2, b, ch[j])[off];

        red[g][slot] = (a0 + a1) + (a2 + a3);
        __syncthreads();
        if (g == 0) {
            vf4 r = (vf4)(0.f);
            #pragma unroll
            for (int gg = 0; gg < 8; ++gg)
                r += red[gg][slot];
            vf4* o = (vf4*)(out + (size_t)(b * k + (k - 1)) * HW);
            o[off] = r;
        }
    } else {
        // ---- copy block: CPB channels
        int cb = bid - ntail;
        int nslots = B * (k - 1);
        int cc[CPB];
        #pragma unroll
        for (int i = 0; i < CPB; ++i) {
            int sl = cb * CPB + i;
            if (sl < nslots) {
                int b = sl / (k - 1);
                int o = sl % (k - 1);
                cc[i] = b * C2 + o;      // temp: slot of idx
            } else cc[i] = -1;
        }
        #pragma unroll
        for (int i = 0; i < CPB; ++i)
            if (cc[i] >= 0) cc[i] = idx[cc[i]] | ((cc[i] / C2) << 16); // pack b
        #pragma unroll
        for (int i = 0; i < CPB; ++i) {
            if (cc[i] < 0) continue;
            int b = cc[i] >> 16;
            int c = cc[i] & 0xFFFF;
            int sl = cb * CPB + i;
            int o  = sl % (k - 1);
            const vf4* src = chan_base(x1, x2, b, c);
            vf4* dst = (vf4*)(out + (size_t)(b * k + o) * HW);
            vf4 v0 = src[t], v1 = src[t + 256], v2 = src[t + 512], v3 = src[t + 768];
            dst[t] = v0; dst[t + 256] = v1; dst[t + 512] = v2; dst[t + 768] = v3;
        }
    }
}

// ---------------------------------------------------------------------------
extern "C" void kernel_launch(void* const* d_in, const int* in_sizes, int n_in,
                              void* d_out, int out_size, void* d_ws, size_t ws_size,
                              hipStream_t stream)
{
    const float* x1 = (const float*)d_in[0];
    const float* x2 = (const float*)d_in[1];
    float* out = (float*)d_out;

    int k = out_size / (B * HW);               // = 256

    float* pooled = (float*)d_ws;              // B*C2 floats = 32 KB
    int*   idx    = (int*)((char*)d_ws + B * C2 * sizeof(float)); // 32 KB

    pool_kernel<<<(B * C2 * QSPLIT) / 256, 256, 0, stream>>>(x1, x2, pooled);
    sort_kernel<<<B, 512, 0, stream>>>(pooled, idx);

    int ncopy = (B * (k - 1) + CPB - 1) / CPB;     // 510
    gather_kernel<<<B * TCHUNK + ncopy, 256, 0, stream>>>(x1, x2, idx, out, k);
}

// Round 7
// 69.673 us; speedup vs baseline: 1.0577x; 1.0577x over previous
//
#include <hip/hip_runtime.h>

#define B   16
#define C1  256          // channels per input
#define C2  512          // total channels after concat
#define HW  4096         // 64*64 pixels per channel
#define TCHUNK 32        // tail pixel-chunks per batch (128 pixels each)
#define CPB 8            // channels copied per copy-block

typedef float vf4 __attribute__((ext_vector_type(4)));

__device__ __forceinline__ const vf4* chan_base(
    const float* __restrict__ x1, const float* __restrict__ x2, int b, int c)
{
    return (const vf4*)((c < C1) ? (x1 + (size_t)(b * C1 + c) * HW)
                                 : (x2 + (size_t)(b * C1 + (c - C1)) * HW));
}

#define GLD(dst, ptr, imm) \
    asm volatile("global_load_dwordx4 %0, %1, off offset:" #imm \
                 : "=&v"(dst) : "v"(ptr) : "memory")
#define WAITCNT(n) do { \
    asm volatile("s_waitcnt vmcnt(" #n ")" ::: "memory"); \
    __builtin_amdgcn_sched_barrier(0); } while (0)

// ---------------------------------------------------------------------------
// Kernel 1: per-(batch, channel) sum over H*W -> pooled[B*C2]
// One WAVE per channel; 16 dwordx4 per lane issued as a depth-8 software
// pipeline via inline asm + counted vmcnt (compiler-proof MLP).
// ---------------------------------------------------------------------------
__global__ __launch_bounds__(256, 4) void pool_kernel(
    const float* __restrict__ x1, const float* __restrict__ x2,
    float* __restrict__ pooled)
{
    int t    = threadIdx.x;
    int wid  = t >> 6;
    int lane = t & 63;
    int bc   = blockIdx.x * 4 + wid;       // grid = 512 -> 0..2047? no: 2048 blocks? see launch
    int b    = bc >> 9;
    int c    = bc & (C2 - 1);
    const float* base = (const float*)chan_base(x1, x2, b, c);

    // group pointers: group g covers bytes [g*4096, g*4096+4096) of the 16 KB
    // channel; lane covers 16 B at +lane*16, loads at +r*1024 (r=0..3).
    const float* p0 = base + lane * 4;
    const float* p1 = p0 + 1024;
    const float* p2 = p0 + 2048;
    const float* p3 = p0 + 3072;

    vf4 r0, r1, r2, r3, r4, r5, r6, r7;
    vf4 acc = (vf4)(0.f);

    // issue G0 + G1  (8 in flight)
    GLD(r0, p0, 0);    GLD(r1, p0, 1024); GLD(r2, p0, 2048); GLD(r3, p0, 3072);
    GLD(r4, p1, 0);    GLD(r5, p1, 1024); GLD(r6, p1, 2048); GLD(r7, p1, 3072);

    WAITCNT(4);                            // G0 ready
    acc += (r0 + r1) + (r2 + r3);
    GLD(r0, p2, 0);    GLD(r1, p2, 1024); GLD(r2, p2, 2048); GLD(r3, p2, 3072);

    WAITCNT(4);                            // G1 ready
    acc += (r4 + r5) + (r6 + r7);
    GLD(r4, p3, 0);    GLD(r5, p3, 1024); GLD(r6, p3, 2048); GLD(r7, p3, 3072);

    WAITCNT(4);                            // G2 ready
    acc += (r0 + r1) + (r2 + r3);

    WAITCNT(0);                            // G3 ready
    acc += (r4 + r5) + (r6 + r7);

    float s = (acc.x + acc.y) + (acc.z + acc.w);
    #pragma unroll
    for (int off = 32; off > 0; off >>= 1)
        s += __shfl_down(s, off, 64);

    if (lane == 0)
        pooled[bc] = s;
}

// ---------------------------------------------------------------------------
// Kernel 2: per-batch stable descending rank-sort of pooled values.
// ---------------------------------------------------------------------------
__global__ __launch_bounds__(512) void sort_kernel(
    const float* __restrict__ pooled, int* __restrict__ idx)
{
    int b = blockIdx.x;
    int t = threadIdx.x;            // 512 threads = one per channel
    __shared__ float sp[C2];
    float v = pooled[b * C2 + t];
    sp[t] = v;
    __syncthreads();
    int rank = 0;
    for (int j = 0; j < C2; ++j) {
        float u = sp[j];
        rank += (u > v) || (u == v && j < t);
    }
    idx[b * C2 + rank] = t;
}

// ---------------------------------------------------------------------------
// Kernel 3: gather channels in sorted order; fold tail sum into channel k-1.
// (unchanged from round 5 — ~20-22 us, near HBM roofline)
// ---------------------------------------------------------------------------
__global__ __launch_bounds__(256) void gather_kernel(
    const float* __restrict__ x1, const float* __restrict__ x2,
    const int* __restrict__ idx, float* __restrict__ out, int k)
{
    int t   = threadIdx.x;
    int bid = blockIdx.x;
    int ntail = B * TCHUNK;

    if (bid < ntail) {
        // ---- tail block
        int b     = bid / TCHUNK;
        int chunk = bid % TCHUNK;
        int g     = t >> 5;          // channel group 0..7
        int slot  = t & 31;          // f4 slot within 128-pixel chunk
        int off   = chunk * 32 + slot;  // f4 index in channel
        int ntc   = C2 - (k - 1);    // 257 tail channels

        __shared__ int ch[C2];
        __shared__ vf4 red[8][32];
        for (int i = t; i < ntc; i += 256)
            ch[i] = idx[b * C2 + (k - 1) + i];
        __syncthreads();

        vf4 a0 = (vf4)(0.f), a1 = (vf4)(0.f), a2 = (vf4)(0.f), a3 = (vf4)(0.f);
        int j = g;
        for (; j + 24 < ntc; j += 32) {
            int c0 = ch[j], c1 = ch[j + 8], c2 = ch[j + 16], c3 = ch[j + 24];
            a0 += chan_base(x1, x2, b, c0)[off];
            a1 += chan_base(x1, x2, b, c1)[off];
            a2 += chan_base(x1, x2, b, c2)[off];
            a3 += chan_base(x1, x2, b, c3)[off];
        }
        for (; j < ntc; j += 8)
            a0 += chan_base(x1, x2, b, ch[j])[off];

        red[g][slot] = (a0 + a1) + (a2 + a3);
        __syncthreads();
        if (g == 0) {
            vf4 r = (vf4)(0.f);
            #pragma unroll
            for (int gg = 0; gg < 8; ++gg)
                r += red[gg][slot];
            vf4* o = (vf4*)(out + (size_t)(b * k + (k - 1)) * HW);
            o[off] = r;
        }
    } else {
        // ---- copy block: CPB channels
        int cb = bid - ntail;
        int nslots = B * (k - 1);
        int cc[CPB];
        #pragma unroll
        for (int i = 0; i < CPB; ++i) {
            int sl = cb * CPB + i;
            if (sl < nslots) {
                int b = sl / (k - 1);
                int o = sl % (k - 1);
                cc[i] = b * C2 + o;      // temp: slot of idx
            } else cc[i] = -1;
        }
        #pragma unroll
        for (int i = 0; i < CPB; ++i)
            if (cc[i] >= 0) cc[i] = idx[cc[i]] | ((cc[i] / C2) << 16); // pack b
        #pragma unroll
        for (int i = 0; i < CPB; ++i) {
            if (cc[i] < 0) continue;
            int b = cc[i] >> 16;
            int c = cc[i] & 0xFFFF;
            int sl = cb * CPB + i;
            int o  = sl % (k - 1);
            const vf4* src = chan_base(x1, x2, b, c);
            vf4* dst = (vf4*)(out + (size_t)(b * k + o) * HW);
            vf4 v0 = src[t], v1 = src[t + 256], v2 = src[t + 512], v3 = src[t + 768];
            dst[t] = v0; dst[t + 256] = v1; dst[t + 512] = v2; dst[t + 768] = v3;
        }
    }
}

// ---------------------------------------------------------------------------
extern "C" void kernel_launch(void* const* d_in, const int* in_sizes, int n_in,
                              void* d_out, int out_size, void* d_ws, size_t ws_size,
                              hipStream_t stream)
{
    const float* x1 = (const float*)d_in[0];
    const float* x2 = (const float*)d_in[1];
    float* out = (float*)d_out;

    int k = out_size / (B * HW);               // = 256

    float* pooled = (float*)d_ws;              // B*C2 floats = 32 KB
    int*   idx    = (int*)((char*)d_ws + B * C2 * sizeof(float)); // 32 KB

    pool_kernel<<<(B * C2) / 4, 256, 0, stream>>>(x1, x2, pooled);   // 2048 blocks? no: 8192/4 = 2048
    sort_kernel<<<B, 512, 0, stream>>>(pooled, idx);

    int ncopy = (B * (k - 1) + CPB - 1) / CPB;     // 510
    gather_kernel<<<B * TCHUNK + ncopy, 256, 0, stream>>>(x1, x2, idx, out, k);
}

// Round 8
// 63.899 us; speedup vs baseline: 1.1533x; 1.0904x over previous
//
#include <hip/hip_runtime.h>

#define B   16
#define C1  256          // channels per input
#define C2  512          // total channels after concat
#define HW  4096         // 64*64 pixels per channel
#define TCHUNK 32        // 128-pixel chunks per image

typedef float vf4 __attribute__((ext_vector_type(4)));

__device__ __forceinline__ const vf4* chan_base(
    const float* __restrict__ x1, const float* __restrict__ x2, int b, int c)
{
    return (const vf4*)((c < C1) ? (x1 + (size_t)(b * C1 + c) * HW)
                                 : (x2 + (size_t)(b * C1 + (c - C1)) * HW));
}

// ---------------------------------------------------------------------------
// K1: fused reduce. Block = (b, 128-pixel chunk). 8 channel-groups x 32 slots.
// Produces: total[b][pix] = sum over ALL 512 channels (per-pixel), and
// partials[b][chunk][c] = sum of channel c over this chunk's 128 pixels.
// Reads each input element exactly once, in the gather-proven access shape.
// ---------------------------------------------------------------------------
__global__ __launch_bounds__(256) void reduce_kernel(
    const float* __restrict__ x1, const float* __restrict__ x2,
    float* __restrict__ total,      // [B][HW]
    float* __restrict__ partials)   // [B][TCHUNK][C2]
{
    int bid   = blockIdx.x;          // 0..511
    int b     = bid / TCHUNK;
    int chunk = bid % TCHUNK;
    int t     = threadIdx.x;
    int g     = t >> 5;              // channel group 0..7
    int slot  = t & 31;              // f4-slot within chunk
    int off   = chunk * 32 + slot;   // f4 index within channel

    float* pp = partials + (size_t)(b * TCHUNK + chunk) * C2;

    vf4 t0 = (vf4)(0.f), t1 = (vf4)(0.f), t2 = (vf4)(0.f), t3 = (vf4)(0.f);

    // group g covers channels g, 8+g, 16+g, ... (64 channels), 4-way ILP
    for (int j = 0; j < 64; j += 4) {
        int c0 = (j + 0) * 8 + g, c1 = (j + 1) * 8 + g;
        int c2 = (j + 2) * 8 + g, c3 = (j + 3) * 8 + g;
        vf4 v0 = chan_base(x1, x2, b, c0)[off];
        vf4 v1 = chan_base(x1, x2, b, c1)[off];
        vf4 v2 = chan_base(x1, x2, b, c2)[off];
        vf4 v3 = chan_base(x1, x2, b, c3)[off];
        t0 += v0; t1 += v1; t2 += v2; t3 += v3;

        float h0 = (v0.x + v0.y) + (v0.z + v0.w);
        float h1 = (v1.x + v1.y) + (v1.z + v1.w);
        float h2 = (v2.x + v2.y) + (v2.z + v2.w);
        float h3 = (v3.x + v3.y) + (v3.z + v3.w);
        // width-32 reduce (each half-wave = one channel group)
        #pragma unroll
        for (int s = 16; s > 0; s >>= 1) {
            h0 += __shfl_down(h0, s, 32);
            h1 += __shfl_down(h1, s, 32);
            h2 += __shfl_down(h2, s, 32);
            h3 += __shfl_down(h3, s, 32);
        }
        if (slot == 0) {
            pp[c0] = h0; pp[c1] = h1; pp[c2] = h2; pp[c3] = h3;
        }
    }

    // per-pixel total: reduce the 8 groups' partial pixel-sums
    __shared__ vf4 red[8][32];
    red[g][slot] = (t0 + t1) + (t2 + t3);
    __syncthreads();
    if (g == 0) {
        vf4 r = (vf4)(0.f);
        #pragma unroll
        for (int gg = 0; gg < 8; ++gg)
            r += red[gg][slot];
        ((vf4*)(total + (size_t)b * HW))[off] = r;
    }
}

// ---------------------------------------------------------------------------
// K2: reduce chunk-partials -> pooled value per channel, then stable
// descending rank-sort. idx[b*C2 + rank] = channel.
// ---------------------------------------------------------------------------
__global__ __launch_bounds__(512) void sort_kernel(
    const float* __restrict__ partials, int* __restrict__ idx)
{
    int b = blockIdx.x;
    int t = threadIdx.x;            // one per channel
    const float* pp = partials + (size_t)b * TCHUNK * C2 + t;
    float v = 0.f;
    #pragma unroll
    for (int ch = 0; ch < TCHUNK; ++ch)
        v += pp[ch * C2];

    __shared__ float sp[C2];
    sp[t] = v;
    __syncthreads();
    int rank = 0;
    for (int j = 0; j < C2; ++j) {
        float u = sp[j];
        rank += (u > v) || (u == v && j < t);
    }
    idx[b * C2 + rank] = t;
}

// ---------------------------------------------------------------------------
// K3: output. Block = (b, 128-pixel chunk). Copies the k-1 head channels in
// rank order (accumulating the per-pixel head sum in registers), then writes
// channel k-1 = total - head_sum. Tail channels are never re-read.
// ---------------------------------------------------------------------------
__global__ __launch_bounds__(256) void output_kernel(
    const float* __restrict__ x1, const float* __restrict__ x2,
    const int* __restrict__ idx, const float* __restrict__ total,
    float* __restrict__ out, int k)
{
    int bid   = blockIdx.x;
    int b     = bid / TCHUNK;
    int chunk = bid % TCHUNK;
    int t     = threadIdx.x;
    int g     = t >> 5;
    int slot  = t & 31;
    int off   = chunk * 32 + slot;
    int nh    = k - 1;               // 255 head channels

    __shared__ int ch[C2 / 2];       // head channel list (k-1 <= 256)
    __shared__ vf4 red[8][32];
    for (int i = t; i < nh; i += 256)
        ch[i] = idx[b * C2 + i];
    __syncthreads();

    vf4 a0 = (vf4)(0.f), a1 = (vf4)(0.f), a2 = (vf4)(0.f), a3 = (vf4)(0.f);
    const size_t ob = (size_t)b * k;
    int r = g;
    for (; r + 24 < nh; r += 32) {
        int c0 = ch[r], c1 = ch[r + 8], c2 = ch[r + 16], c3 = ch[r + 24];
        vf4 v0 = chan_base(x1, x2, b, c0)[off];
        vf4 v1 = chan_base(x1, x2, b, c1)[off];
        vf4 v2 = chan_base(x1, x2, b, c2)[off];
        vf4 v3 = chan_base(x1, x2, b, c3)[off];
        ((vf4*)(out + (ob + r     ) * HW))[off] = v0;
        ((vf4*)(out + (ob + r +  8) * HW))[off] = v1;
        ((vf4*)(out + (ob + r + 16) * HW))[off] = v2;
        ((vf4*)(out + (ob + r + 24) * HW))[off] = v3;
        a0 += v0; a1 += v1; a2 += v2; a3 += v3;
    }
    for (; r < nh; r += 8) {
        int c0 = ch[r];
        vf4 v0 = chan_base(x1, x2, b, c0)[off];
        ((vf4*)(out + (ob + r) * HW))[off] = v0;
        a0 += v0;
    }

    red[g][slot] = (a0 + a1) + (a2 + a3);
    __syncthreads();
    if (g == 0) {
        vf4 hsum = (vf4)(0.f);
        #pragma unroll
        for (int gg = 0; gg < 8; ++gg)
            hsum += red[gg][slot];
        vf4 tt = ((const vf4*)(total + (size_t)b * HW))[off];
        ((vf4*)(out + (ob + (k - 1)) * HW))[off] = tt - hsum;
    }
}

// ---------------------------------------------------------------------------
extern "C" void kernel_launch(void* const* d_in, const int* in_sizes, int n_in,
                              void* d_out, int out_size, void* d_ws, size_t ws_size,
                              hipStream_t stream)
{
    const float* x1 = (const float*)d_in[0];
    const float* x2 = (const float*)d_in[1];
    float* out = (float*)d_out;

    int k = out_size / (B * HW);               // = 256

    // ws layout: idx[B*C2] | total[B*HW] | partials[B*TCHUNK*C2]  (~1.3 MB)
    int*   idx      = (int*)d_ws;
    float* total    = (float*)((char*)d_ws + B * C2 * sizeof(int));
    float* partials = total + (size_t)B * HW;

    reduce_kernel<<<B * TCHUNK, 256, 0, stream>>>(x1, x2, total, partials);
    sort_kernel<<<B, 512, 0, stream>>>(partials, idx);
    output_kernel<<<B * TCHUNK, 256, 0, stream>>>(x1, x2, idx, total, out, k);
}

// Round 9
// 63.376 us; speedup vs baseline: 1.1628x; 1.0082x over previous
//
#include <hip/hip_runtime.h>

#define B   16
#define C1  256          // channels per input
#define C2  512          // total channels after concat
#define HW  4096         // 64*64 pixels per channel
#define TCHUNK 32        // 128-pixel chunks per image
#define PAD 33           // LDS row stride (33 % 32 == 1 -> conflict-free)

typedef float vf4 __attribute__((ext_vector_type(4)));

__device__ __forceinline__ const vf4* chan_base(
    const float* __restrict__ x1, const float* __restrict__ x2, int b, int c)
{
    return (const vf4*)((c < C1) ? (x1 + (size_t)(b * C1 + c) * HW)
                                 : (x2 + (size_t)(b * C1 + (c - C1)) * HW));
}

// ---------------------------------------------------------------------------
// K1: fused reduce. Block = (b, 128-pixel chunk). 8 channel-groups x 32 slots.
// Main loop is PURE load+add+ds_write (no cross-lane ops, no vmcnt-serial
// shuffle trees). Per-lane 4-pixel channel sums land in padded LDS; all
// reductions happen once after the loop.
// Outputs: total[b][pix] (sum over all 512 channels), partials[b][chunk][c].
// ---------------------------------------------------------------------------
__global__ __launch_bounds__(256) void reduce_kernel(
    const float* __restrict__ x1, const float* __restrict__ x2,
    float* __restrict__ total,      // [B][HW]
    float* __restrict__ partials)   // [B][TCHUNK][C2]
{
    int bid   = blockIdx.x;          // 0..511
    int b     = bid / TCHUNK;
    int chunk = bid % TCHUNK;
    int t     = threadIdx.x;
    int g     = t >> 5;              // channel group 0..7
    int slot  = t & 31;              // f4-slot within chunk
    int off   = chunk * 32 + slot;   // f4 index within channel

    __shared__ float pacc[C2 * PAD];   // 512*33*4 = 67.6 KB
    __shared__ vf4   red[8][32];       // 4 KB

    vf4 acc[8];
    #pragma unroll
    for (int m = 0; m < 8; ++m) acc[m] = (vf4)(0.f);

    // group g owns channels c = i*8+g, i=0..63; 8 channels per iteration.
    #pragma unroll 2
    for (int j = 0; j < 8; ++j) {
        vf4 v[8];
        #pragma unroll
        for (int m = 0; m < 8; ++m) {
            int c = (j * 8 + m) * 8 + g;
            v[m] = chan_base(x1, x2, b, c)[off];
        }
        #pragma unroll
        for (int m = 0; m < 8; ++m) {
            int c = (j * 8 + m) * 8 + g;
            acc[m] += v[m];
            pacc[c * PAD + slot] = (v[m].x + v[m].y) + (v[m].z + v[m].w);
        }
    }

    // per-pixel total partial into red
    red[g][slot] = ((acc[0] + acc[1]) + (acc[2] + acc[3]))
                 + ((acc[4] + acc[5]) + (acc[6] + acc[7]));
    __syncthreads();

    if (g == 0) {
        vf4 r = (vf4)(0.f);
        #pragma unroll
        for (int gg = 0; gg < 8; ++gg)
            r += red[gg][slot];
        ((vf4*)(total + (size_t)b * HW))[off] = r;
    }

    // per-channel partials: thread t reduces channels t and t+256
    float s0 = 0.f, s1 = 0.f;
    #pragma unroll
    for (int s = 0; s < 32; ++s) {
        s0 += pacc[t * PAD + s];
        s1 += pacc[(t + 256) * PAD + s];
    }
    float* pp = partials + (size_t)(b * TCHUNK + chunk) * C2;
    pp[t]       = s0;
    pp[t + 256] = s1;
}

// ---------------------------------------------------------------------------
// K2: reduce chunk-partials -> pooled value per channel, then stable
// descending rank-sort. idx[b*C2 + rank] = channel.
// ---------------------------------------------------------------------------
__global__ __launch_bounds__(512) void sort_kernel(
    const float* __restrict__ partials, int* __restrict__ idx)
{
    int b = blockIdx.x;
    int t = threadIdx.x;            // one per channel
    const float* pp = partials + (size_t)b * TCHUNK * C2 + t;
    float v = 0.f;
    #pragma unroll
    for (int ch = 0; ch < TCHUNK; ++ch)
        v += pp[ch * C2];

    __shared__ float sp[C2];
    sp[t] = v;
    __syncthreads();
    int rank = 0;
    for (int j = 0; j < C2; ++j) {
        float u = sp[j];
        rank += (u > v) || (u == v && j < t);
    }
    idx[b * C2 + rank] = t;
}

// ---------------------------------------------------------------------------
// K3: output. Block = (b, 128-pixel chunk). Copies the k-1 head channels in
// rank order (accumulating the per-pixel head sum in registers), then writes
// channel k-1 = total - head_sum. Tail channels are never re-read.
// ---------------------------------------------------------------------------
__global__ __launch_bounds__(256) void output_kernel(
    const float* __restrict__ x1, const float* __restrict__ x2,
    const int* __restrict__ idx, const float* __restrict__ total,
    float* __restrict__ out, int k)
{
    int bid   = blockIdx.x;
    int b     = bid / TCHUNK;
    int chunk = bid % TCHUNK;
    int t     = threadIdx.x;
    int g     = t >> 5;
    int slot  = t & 31;
    int off   = chunk * 32 + slot;
    int nh    = k - 1;               // 255 head channels

    __shared__ int ch[C2 / 2];       // head channel list (k-1 <= 256)
    __shared__ vf4 red[8][32];
    for (int i = t; i < nh; i += 256)
        ch[i] = idx[b * C2 + i];
    __syncthreads();

    vf4 a0 = (vf4)(0.f), a1 = (vf4)(0.f), a2 = (vf4)(0.f), a3 = (vf4)(0.f);
    const size_t ob = (size_t)b * k;
    int r = g;
    for (; r + 24 < nh; r += 32) {
        int c0 = ch[r], c1 = ch[r + 8], c2 = ch[r + 16], c3 = ch[r + 24];
        vf4 v0 = chan_base(x1, x2, b, c0)[off];
        vf4 v1 = chan_base(x1, x2, b, c1)[off];
        vf4 v2 = chan_base(x1, x2, b, c2)[off];
        vf4 v3 = chan_base(x1, x2, b, c3)[off];
        ((vf4*)(out + (ob + r     ) * HW))[off] = v0;
        ((vf4*)(out + (ob + r +  8) * HW))[off] = v1;
        ((vf4*)(out + (ob + r + 16) * HW))[off] = v2;
        ((vf4*)(out + (ob + r + 24) * HW))[off] = v3;
        a0 += v0; a1 += v1; a2 += v2; a3 += v3;
    }
    for (; r < nh; r += 8) {
        int c0 = ch[r];
        vf4 v0 = chan_base(x1, x2, b, c0)[off];
        ((vf4*)(out + (ob + r) * HW))[off] = v0;
        a0 += v0;
    }

    red[g][slot] = (a0 + a1) + (a2 + a3);
    __syncthreads();
    if (g == 0) {
        vf4 hsum = (vf4)(0.f);
        #pragma unroll
        for (int gg = 0; gg < 8; ++gg)
            hsum += red[gg][slot];
        vf4 tt = ((const vf4*)(total + (size_t)b * HW))[off];
        ((vf4*)(out + (ob + (k - 1)) * HW))[off] = tt - hsum;
    }
}

// ---------------------------------------------------------------------------
extern "C" void kernel_launch(void* const* d_in, const int* in_sizes, int n_in,
                              void* d_out, int out_size, void* d_ws, size_t ws_size,
                              hipStream_t stream)
{
    const float* x1 = (const float*)d_in[0];
    const float* x2 = (const float*)d_in[1];
    float* out = (float*)d_out;

    int k = out_size / (B * HW);               // = 256

    // ws layout: idx[B*C2] | total[B*HW] | partials[B*TCHUNK*C2]  (~1.3 MB)
    int*   idx      = (int*)d_ws;
    float* total    = (float*)((char*)d_ws + B * C2 * sizeof(int));
    float* partials = total + (size_t)B * HW;

    reduce_kernel<<<B * TCHUNK, 256, 0, stream>>>(x1, x2, total, partials);
    sort_kernel<<<B, 512, 0, stream>>>(partials, idx);
    output_kernel<<<B * TCHUNK, 256, 0, stream>>>(x1, x2, idx, total, out, k);
}